// Round 1
// baseline (455.366 us; speedup 1.0000x reference)
//
#include <hip/hip_runtime.h>
#include <math.h>

typedef _Float16 f16;
typedef _Float16 __attribute__((ext_vector_type(8))) f16x8;
typedef _Float16 __attribute__((ext_vector_type(4))) f16x4;
typedef float __attribute__((ext_vector_type(4))) f32x4;
typedef unsigned int u32;

#define MFMA(a, b, c) __builtin_amdgcn_mfma_f32_16x16x32_f16(a, b, c, 0, 0, 0)

typedef const u32 __attribute__((address_space(1))) gas_u32;
typedef u32 __attribute__((address_space(3))) las_u32;

// global -> LDS direct copy, 16 B per lane. LDS dest must be wave-uniform base + lane*16.
__device__ __forceinline__ void gload_lds16(const void* gptr, void* lptr) {
  unsigned long long gi = (unsigned long long)gptr;
  u32 li = (u32)(unsigned long long)lptr;  // low 32 bits of flat LDS addr == LDS offset
  __builtin_amdgcn_global_load_lds((gas_u32*)gi, (las_u32*)li, 16, 0, 0);
}

// ---------------- cast f32 -> f16, vectorized x4 ----------------
__global__ void castk(const float* __restrict__ in, f16* __restrict__ out, int n4) {
  int i = blockIdx.x * blockDim.x + threadIdx.x;
  if (i >= n4) return;
  float4 f = ((const float4*)in)[i];
  f16x4 h;
  h[0] = (f16)f.x; h[1] = (f16)f.y; h[2] = (f16)f.z; h[3] = (f16)f.w;
  *(f16x4*)(out + 4 * (size_t)i) = h;
}

// ---------------- GEMM: C[M,N] = A[M,K] @ B[N,K]^T + bias[N] ----------------
// 128x128 tile, BK=32, 4 waves (each a 64x64 subtile of 4x4 16x16 frags).
// EPI==0: write f32 to Of.  EPI==1: scatter f16 to q/k/v in [B,H,T,64] layout.
template <int EPI>
__global__ __launch_bounds__(256) void gemm_bt(
    const f16* __restrict__ A, const f16* __restrict__ Bw,
    const float* __restrict__ bias,
    f16* __restrict__ Oq, f16* __restrict__ Ok, f16* __restrict__ Ov,
    float* __restrict__ Of,
    const int M, const int N, const int K) {
  __shared__ __align__(16) f16 As[128 * 32];
  __shared__ __align__(16) f16 Bs[128 * 32];
  const int tid = threadIdx.x;
  const int l = tid & 63;
  const int w = tid >> 6;
  const int wr = w >> 1, wc = w & 1;
  const int lr = l & 15, lg = l >> 4;
  const int m0 = blockIdx.y * 128;
  const int n0 = blockIdx.x * 128;

  const int srow = tid >> 2;         // 0..63
  const int scol = (tid & 3) * 8;    // 0,8,16,24

  f32x4 acc[4][4];
#pragma unroll
  for (int i = 0; i < 4; ++i)
#pragma unroll
    for (int j = 0; j < 4; ++j) acc[i][j] = (f32x4){0.f, 0.f, 0.f, 0.f};

  for (int k0 = 0; k0 < K; k0 += 32) {
    gload_lds16(A + (size_t)(m0 + srow) * K + k0 + scol, As + tid * 8);
    gload_lds16(A + (size_t)(m0 + srow + 64) * K + k0 + scol, As + 2048 + tid * 8);
    gload_lds16(Bw + (size_t)(n0 + srow) * K + k0 + scol, Bs + tid * 8);
    gload_lds16(Bw + (size_t)(n0 + srow + 64) * K + k0 + scol, Bs + 2048 + tid * 8);
    __syncthreads();  // compiler drains vmcnt before s_barrier

    f16x8 af[4], bfr[4];
#pragma unroll
    for (int i = 0; i < 4; ++i)
      af[i] = *(const f16x8*)&As[(wr * 64 + i * 16 + lr) * 32 + lg * 8];
#pragma unroll
    for (int j = 0; j < 4; ++j)
      bfr[j] = *(const f16x8*)&Bs[(wc * 64 + j * 16 + lr) * 32 + lg * 8];
#pragma unroll
    for (int i = 0; i < 4; ++i)
#pragma unroll
      for (int j = 0; j < 4; ++j) acc[i][j] = MFMA(af[i], bfr[j], acc[i][j]);
    __syncthreads();
  }

  // Epilogue. D layout: col = lane&15, row = (lane>>4)*4 + reg.
#pragma unroll
  for (int i = 0; i < 4; ++i) {
    const int rbase = m0 + wr * 64 + i * 16 + lg * 4;
#pragma unroll
    for (int j = 0; j < 4; ++j) {
      const int col = n0 + wc * 64 + j * 16 + lr;
      const float bv = bias[col];
#pragma unroll
      for (int jj = 0; jj < 4; ++jj) {
        const int r = rbase + jj;
        const float val = acc[i][j][jj] + bv;
        if (EPI == 0) {
          Of[(size_t)r * N + col] = val;
        } else {
          const int which = col >> 10;
          const int inner = col & 1023;
          const int h = inner >> 6;
          const int d = inner & 63;
          f16* dst = (which == 0) ? Oq : (which == 1) ? Ok : Ov;
          // [B,H,T,64]: b = r>>11, t = r&2047
          dst[(size_t)(((r >> 11) * 16 + h) * 2048 + (r & 2047)) * 64 + d] = (f16)val;
        }
      }
    }
  }
}

// ---------------- flash attention (causal), hd=64 ----------------
// grid: (T/64, B*H). 256 threads = 4 waves; wave w owns q rows [q0+16w, q0+16w+16).
// KV blocks of 64 staged in LDS (K row-major, V transposed), pad-72 rows.
__global__ __launch_bounds__(256) void attn_fwd(
    const f16* __restrict__ Qg, const f16* __restrict__ Kg,
    const f16* __restrict__ Vg, f16* __restrict__ Yg) {
  const int T = 2048;
  const int qt = blockIdx.x;
  const int bh = blockIdx.y;
  const int q0 = qt * 64;
  const int tid = threadIdx.x;
  const int w = tid >> 6;
  const int l = tid & 63;
  const int lr = l & 15;
  const int lg = l >> 4;

  const f16* Qh = Qg + (size_t)bh * T * 64;
  const f16* Kh = Kg + (size_t)bh * T * 64;
  const f16* Vh = Vg + (size_t)bh * T * 64;

  __shared__ __align__(16) f16 Ks[64][72];
  __shared__ __align__(16) f16 Vt[64][72];   // transposed: Vt[d][key]
  __shared__ __align__(16) f16 Ps[4][16][72];

  const float SCL = 0.125f * 1.44269504088896f;  // 1/sqrt(64) * log2(e)

  // Q A-fragments, pre-scaled: lane holds Q[q0+16w+lr][kk*32 + lg*8 .. +8]
  f16x8 qf[2];
  {
    const f16* qp = Qh + (size_t)(q0 + w * 16 + lr) * 64 + lg * 8;
    f16x8 t0 = *(const f16x8*)qp;
    f16x8 t1 = *(const f16x8*)(qp + 32);
#pragma unroll
    for (int j = 0; j < 8; ++j) {
      t0[j] = (f16)(SCL * (float)t0[j]);
      t1[j] = (f16)(SCL * (float)t1[j]);
    }
    qf[0] = t0; qf[1] = t1;
  }

  f32x4 Yacc[4];
#pragma unroll
  for (int fd = 0; fd < 4; ++fd) Yacc[fd] = (f32x4){0.f, 0.f, 0.f, 0.f};
  float mrow[4] = {-1e30f, -1e30f, -1e30f, -1e30f};
  float lrow[4] = {0.f, 0.f, 0.f, 0.f};

  for (int kb = 0; kb <= q0; kb += 64) {
    const bool diag = (kb == q0);
    __syncthreads();  // previous iteration's LDS reads done before restage
    {
      // stage K rows (coalesced 128B per row)
      const int key = tid >> 3;
      const int d0 = (tid & 7) * 8;
#pragma unroll
      for (int r2 = 0; r2 < 2; ++r2) {
        f16x8 kv = *(const f16x8*)(Kh + (size_t)(kb + key + 32 * r2) * 64 + d0);
        *(f16x8*)&Ks[key + 32 * r2][d0] = kv;
      }
      // stage V transposed; writes conflict-free (lane -> consecutive columns)
#pragma unroll
      for (int r2 = 0; r2 < 2; ++r2) {
        const int vd0 = w * 8 + 32 * r2;
        f16x8 vv = *(const f16x8*)(Vh + (size_t)(kb + l) * 64 + vd0);
#pragma unroll
        for (int j = 0; j < 8; ++j) Vt[vd0 + j][l] = vv[j];
      }
    }
    __syncthreads();

    // S = (scaled Q) K^T.  D layout: row q = lg*4+jj, col key = kc*16+lr
    f32x4 S[4];
#pragma unroll
    for (int kc = 0; kc < 4; ++kc) {
      f16x8 kf0 = *(const f16x8*)&Ks[kc * 16 + lr][lg * 8];
      f16x8 kf1 = *(const f16x8*)&Ks[kc * 16 + lr][32 + lg * 8];
      f32x4 z = (f32x4){0.f, 0.f, 0.f, 0.f};
      z = MFMA(qf[0], kf0, z);
      z = MFMA(qf[1], kf1, z);
      S[kc] = z;
    }

    float p[4][4];
    float rmax[4] = {-1e30f, -1e30f, -1e30f, -1e30f};
#pragma unroll
    for (int kc = 0; kc < 4; ++kc)
#pragma unroll
      for (int jj = 0; jj < 4; ++jj) {
        float s = S[kc][jj];
        if (diag && (kc * 16 + lr) > (w * 16 + lg * 4 + jj)) s = -1e30f;
        p[kc][jj] = s;
        rmax[jj] = fmaxf(rmax[jj], s);
      }
    // row-reduce across the 16 lanes sharing lg (lr = bits 0..3)
#pragma unroll
    for (int jj = 0; jj < 4; ++jj) {
      rmax[jj] = fmaxf(rmax[jj], __shfl_xor(rmax[jj], 1));
      rmax[jj] = fmaxf(rmax[jj], __shfl_xor(rmax[jj], 2));
      rmax[jj] = fmaxf(rmax[jj], __shfl_xor(rmax[jj], 4));
      rmax[jj] = fmaxf(rmax[jj], __shfl_xor(rmax[jj], 8));
    }
    float corr[4];
#pragma unroll
    for (int jj = 0; jj < 4; ++jj) {
      float mnew = fmaxf(mrow[jj], rmax[jj]);
      corr[jj] = exp2f(mrow[jj] - mnew);
      mrow[jj] = mnew;
    }
#pragma unroll
    for (int jj = 0; jj < 4; ++jj) {
      float rs = 0.f;
#pragma unroll
      for (int kc = 0; kc < 4; ++kc) {
        float pv = exp2f(p[kc][jj] - mrow[jj]);
        p[kc][jj] = pv;
        rs += pv;
      }
      rs += __shfl_xor(rs, 1);
      rs += __shfl_xor(rs, 2);
      rs += __shfl_xor(rs, 4);
      rs += __shfl_xor(rs, 8);
      lrow[jj] = lrow[jj] * corr[jj] + rs;
#pragma unroll
      for (int fd = 0; fd < 4; ++fd) Yacc[fd][jj] *= corr[jj];
    }
    // bounce P through LDS to A-operand layout (per-wave buffer; in-order wave LDS)
#pragma unroll
    for (int kc = 0; kc < 4; ++kc)
#pragma unroll
      for (int jj = 0; jj < 4; ++jj)
        Ps[w][lg * 4 + jj][kc * 16 + lr] = (f16)p[kc][jj];

    f16x8 pf0 = *(const f16x8*)&Ps[w][lr][lg * 8];
    f16x8 pf1 = *(const f16x8*)&Ps[w][lr][32 + lg * 8];
#pragma unroll
    for (int fd = 0; fd < 4; ++fd) {
      f16x8 vf0 = *(const f16x8*)&Vt[fd * 16 + lr][lg * 8];
      f16x8 vf1 = *(const f16x8*)&Vt[fd * 16 + lr][32 + lg * 8];
      Yacc[fd] = MFMA(pf0, vf0, Yacc[fd]);
      Yacc[fd] = MFMA(pf1, vf1, Yacc[fd]);
    }
  }

  // epilogue: y[b, t, h*64 + d] (f16), normalized
  const int bI = bh >> 4, hI = bh & 15;
#pragma unroll
  for (int jj = 0; jj < 4; ++jj) {
    const float inv = 1.f / lrow[jj];
    const int t = q0 + w * 16 + lg * 4 + jj;
    f16* yp = Yg + (size_t)(bI * 2048 + t) * 1024 + hI * 64 + lr;
#pragma unroll
    for (int fd = 0; fd < 4; ++fd) yp[fd * 16] = (f16)(Yacc[fd][jj] * inv);
  }
}

// ---------------- launch ----------------
extern "C" void kernel_launch(void* const* d_in, const int* in_sizes, int n_in,
                              void* d_out, int out_size, void* d_ws, size_t ws_size,
                              hipStream_t stream) {
  (void)in_sizes; (void)n_in; (void)out_size; (void)ws_size;
  const float* x      = (const float*)d_in[0];
  const float* w_attn = (const float*)d_in[1];
  const float* b_attn = (const float*)d_in[2];
  const float* w_proj = (const float*)d_in[3];
  const float* b_proj = (const float*)d_in[4];
  float* out = (float*)d_out;

  const int Bz = 4, T = 2048, Cc = 1024;
  const int M = Bz * T;  // 8192

  f16* ws  = (f16*)d_ws;
  f16* wab = ws;                              // w_attn f16: 3C*C
  f16* wpb = wab + (size_t)3 * Cc * Cc;       // w_proj f16: C*C
  f16* qb  = wpb + (size_t)Cc * Cc;           // q [B,H,T,64]
  f16* kb  = qb + (size_t)M * Cc;             // k
  f16* vb  = kb + (size_t)M * Cc;             // v
  f16* xb  = vb + (size_t)M * Cc;             // x f16; reused as attention output y
  // total: 37,748,736 f16 = 75.5 MB

  castk<<<dim3((M * Cc / 4 + 255) / 256), 256, 0, stream>>>(x, xb, M * Cc / 4);
  castk<<<dim3((3 * Cc * Cc / 4 + 255) / 256), 256, 0, stream>>>(w_attn, wab, 3 * Cc * Cc / 4);
  castk<<<dim3((Cc * Cc / 4 + 255) / 256), 256, 0, stream>>>(w_proj, wpb, Cc * Cc / 4);

  gemm_bt<1><<<dim3(3 * Cc / 128, M / 128), 256, 0, stream>>>(
      xb, wab, b_attn, qb, kb, vb, nullptr, M, 3 * Cc, Cc);

  attn_fwd<<<dim3(T / 64, Bz * 16), 256, 0, stream>>>(qb, kb, vb, xb);

  gemm_bt<0><<<dim3(Cc / 128, M / 128), 256, 0, stream>>>(
      xb, wpb, b_proj, nullptr, nullptr, nullptr, out, M, Cc, Cc);
}